// Round 9
// baseline (133.346 us; speedup 1.0000x reference)
//
#include <hip/hip_runtime.h>

using bf16x8 = __attribute__((ext_vector_type(8))) short;
using f32x4  = __attribute__((ext_vector_type(4))) float;
typedef unsigned short u16;
typedef __attribute__((ext_vector_type(8))) unsigned short u16x8;

__device__ __forceinline__ u16 f2b(float f){
  unsigned int i=__float_as_uint(f);
  return (u16)((i + 0x7FFFu + ((i>>16)&1u))>>16);
}
__device__ __forceinline__ float b2f(u16 u){
  union{unsigned int i; float f;}v; v.i=((unsigned int)u)<<16; return v.f;
}
__device__ __forceinline__ void async16(const void* g, void* l){
  __builtin_amdgcn_global_load_lds((__attribute__((address_space(1))) void*)(g),
                                   (__attribute__((address_space(3))) void*)(l), 16, 0, 0);
}
__device__ __forceinline__ float gelu_tanh(float v){
  float u = v*(0.7978845608f + 0.0356774081f*v*v);
  float e = __expf(-2.0f*fabsf(u));
  float th = (1.0f-e)/(1.0f+e);
  th = (u<0.f)? -th : th;
  return 0.5f*v*(1.0f+th);
}

// ---------- prep: weights -> bf16 LDS-image order; zero vb3 planar pad ----------
__global__ void prep_kernel(const float* __restrict__ wqkv, const float* __restrict__ wproj,
                            const float* __restrict__ wfc1, const float* __restrict__ wfc2,
                            u16* __restrict__ tqkv, u16* __restrict__ tproj,
                            u16* __restrict__ tfc1, u16* __restrict__ tfc2,
                            u16* __restrict__ vb3)
{
  int idx = blockIdx.x*256 + threadIdx.x;
  if (idx < 49152){
    int nc = idx>>14, r = idx&16383, i = r>>3, e = r&7, n = i&127, c = i>>7;
    tqkv[idx] = f2b(wqkv[(c*8+e)*384 + nc*128 + n]);
  } else if (idx < 65536){
    int r = idx-49152; int i=r>>3, e=r&7, n=i&127, c=i>>7;
    tproj[r] = f2b(wproj[(c*8+e)*128 + n]);
  } else if (idx < 131072){
    int t = idx-65536; int nc=t>>14, r=t&16383, i=r>>3, e=r&7, n=i&127, c=i>>7;
    tfc1[t] = f2b(wfc1[(c*8+e)*512 + nc*128 + n]);
  } else if (idx < 196608){
    int t = idx-131072; int nc=t>>14, r=t&16383, i=r>>3, e=r&7, n=i&127, c=i>>7;
    tfc2[t] = f2b(wfc2[(nc*128 + c*8 + e)*128 + n]);
  } else {
    int zi = idx - 196608;            // < 262144 : zero the 4 MB planar V
    u16x8 z = {0,0,0,0,0,0,0,0};
    ((u16x8*)vb3)[zi] = z;
  }
}

// aout layout: per 32-token tile, c-major chunks:
//   u16 index = ((tok>>5)*16 + (ch>>3))*256 + (tok&31)*8 + (ch&7)
// vb3 layout: planar padded: [(b*4+h)*32+ch][ (y+3)*64 + (x+3) ]  (4 MB, borders zero)

// ---------- K2: LN1 + one QKV chunk GEMM. 32-token tile, grid (392, 3) ----------
__global__ __launch_bounds__(256)
void qkv_ln_kernel(const float* __restrict__ x,
                   const float* __restrict__ ln1w, const float* __restrict__ ln1b,
                   const u16* __restrict__ tqkv, const float* __restrict__ bqkv,
                   u16* __restrict__ qb, u16* __restrict__ kb, u16* __restrict__ vb3)
{
  __shared__ __align__(16) char smem[40960];
  char* lA = smem;            // 32x128 bf16 c-major chunks (8 KB)
  char* lB = smem + 8192;     // 128x128 bf16 c-major chunks (32 KB)

  const int tid = threadIdx.x;
  const int lane = tid&63, wid = tid>>6;
  const int quad = lane>>4, lrow = lane&15;
  const int m0 = blockIdx.x*32;
  const int nc = blockIdx.y;
  const int wm = (wid&1)*16, wn = (wid>>1)*64;

  #pragma unroll
  for (int kk=0;kk<8;kk++){
    int i = tid + kk*256;
    async16(tqkv + (size_t)nc*16384 + i*8, lB + i*16);
  }

  {
    const int row = tid>>3, g = tid&7;
    float xv[16];
    const float4* xr = (const float4*)(x + (size_t)(m0+row)*128 + g*16);
    float s=0.f, sq=0.f;
    #pragma unroll
    for (int c4=0;c4<4;c4++){
      float4 t = xr[c4];
      xv[c4*4]=t.x; xv[c4*4+1]=t.y; xv[c4*4+2]=t.z; xv[c4*4+3]=t.w;
      s += t.x+t.y+t.z+t.w;
      sq += t.x*t.x+t.y*t.y+t.z*t.z+t.w*t.w;
    }
    s  += __shfl_xor(s,1);  s  += __shfl_xor(s,2);  s  += __shfl_xor(s,4);
    sq += __shfl_xor(sq,1); sq += __shfl_xor(sq,2); sq += __shfl_xor(sq,4);
    float mean = s*0.0078125f;
    float rstd = rsqrtf(sq*0.0078125f - mean*mean + 1e-5f);
    const float4* wr = (const float4*)(ln1w + g*16);
    const float4* br = (const float4*)(ln1b + g*16);
    u16 nv[16];
    #pragma unroll
    for (int c4=0;c4<4;c4++){
      float4 w4 = wr[c4], b4 = br[c4];
      nv[c4*4]   = f2b((xv[c4*4]  -mean)*rstd*w4.x + b4.x);
      nv[c4*4+1] = f2b((xv[c4*4+1]-mean)*rstd*w4.y + b4.y);
      nv[c4*4+2] = f2b((xv[c4*4+2]-mean)*rstd*w4.z + b4.z);
      nv[c4*4+3] = f2b((xv[c4*4+3]-mean)*rstd*w4.w + b4.w);
    }
    #pragma unroll
    for (int cc=0;cc<2;cc++){
      u16x8 pk;
      #pragma unroll
      for (int e=0;e<8;e++) pk[e] = nv[cc*8+e];
      *(u16x8*)(lA + (((g*2+cc)*32 + row)<<4)) = pk;
    }
  }
  __syncthreads();

  f32x4 acc[4] = {};
  #pragma unroll
  for (int ks=0;ks<4;ks++){
    bf16x8 af = ((const bf16x8*)lA)[(ks*4+quad)*32 + wm + lrow];
    #pragma unroll
    for (int j=0;j<4;j++){
      bf16x8 bfr = ((const bf16x8*)lB)[(ks*4+quad)*128 + wn + j*16 + lrow];
      acc[j] = __builtin_amdgcn_mfma_f32_16x16x32_bf16(af, bfr, acc[j], 0,0,0);
    }
  }

  const float scale = 0.17677669529663687f;
  #pragma unroll
  for (int j=0;j<4;j++){
    int col = wn + j*16 + lrow;
    float bia = bqkv[nc*128 + col];
    #pragma unroll
    for (int r=0;r<4;r++){
      int row = m0 + wm + quad*4 + r;
      float val = acc[j][r] + bia;
      if (nc==0){
        qb[(size_t)row*128 + col] = f2b(val*scale);
      } else if (nc==1){
        kb[(size_t)row*128 + col] = f2b(val);
      } else {
        int hh = col>>5, ch = col&31;
        int bq = row/3136, rem = row - bq*3136;
        int yy = rem/56, xx = rem - yy*56;
        vb3[(size_t)(((bq*4+hh)*32 + ch)<<12) + (yy+3)*64 + (xx+3)] = f2b(val);
      }
    }
  }
}

// ---------- K3: MFMA neighborhood attention, pos16 strip layout ----------
// pos16 = hy*16 + hx (hx<14 valid). Wave w: pixels rows 2w,2w+1; strip pos16 in
// [32w, 32w+128) = 8 MFMA col-groups. Masked cols -> -1e30 -> P=0 (no zero fills).
#define KT_S 40    // kt stride (u16)
#define VT_S 232   // vt stride (u16)
#define P_S  152   // P stride (u16)
__global__ __launch_bounds__(256)
void attn_kernel(const u16* __restrict__ qb, const u16* __restrict__ kb,
                 const u16* __restrict__ vb3, const float* __restrict__ rpb,
                 u16* __restrict__ aout)
{
  __shared__ __align__(16) char smem[52424];
  u16*  kt   = (u16*)smem;                 // [224][KT_S]
  u16*  vt   = (u16*)(smem + 17920);       // [32][VT_S]
  u16*  Pm   = (u16*)(smem + 32768);       // 4 waves x [16][P_S]
  float* srpb= (float*)(smem + 52224);     // 49 floats

  const int tid = threadIdx.x;
  const int tile = blockIdx.x, bh = blockIdx.y;
  const int b = bh>>2, h = bh&3;
  const int ty = (tile/7)*8, tx = (tile%7)*8;
  const int lane = tid&63, wid = tid>>6;
  const int quad = lane>>4, lrow = lane&15;

  // ---- K staging: pos16-major [224][32ch], skip hx>=14 (masked later) ----
  #pragma unroll
  for (int kk=0;kk<4;kk++){
    int i = tid + kk*256;
    if (i < 896){
      int pos16 = i>>2, oct = i&3;
      int hx = pos16&15, hy = pos16>>4;
      if (hx < 14){
        int gy = ty+hy-3, gx = tx+hx-3;
        u16x8 kv = {0,0,0,0,0,0,0,0};
        if ((unsigned)gy<56u && (unsigned)gx<56u)
          kv = *(const u16x8*)(kb + ((size_t)(b*3136 + gy*56 + gx)*128 + h*32 + oct*8));
        *(u16x8*)(kt + pos16*KT_S + oct*8) = kv;
      }
    }
  }
  // ---- V staging: straight vector copy from planar padded vb3 ----
  #pragma unroll
  for (int kk=0;kk<4;kk++){
    int i = tid + kk*256;
    if (i < 896){
      int lo = i&1, t2 = i>>1;          // t2 < 448
      int ch = t2/14, hy = t2 - ch*14;
      *(u16x8*)(vt + ch*VT_S + hy*16 + lo*8) =
        *(const u16x8*)(vb3 + ((size_t)(bh*32 + ch)<<12) + (ty+hy)*64 + tx + lo*8);
    }
  }
  if (tid < 49) srpb[tid] = rpb[h*49 + tid];
  __syncthreads();

  // ---- Q fragment ----
  const int pxq = wid*16 + lrow;
  const int tokq = b*3136 + (ty + (pxq>>3))*56 + tx + (pxq&7);
  bf16x8 qf = *(const bf16x8*)(qb + (size_t)tokq*128 + h*32 + quad*8);

  // ---- scores: 8 MFMAs over the 128-pos16 strip ----
  f32x4 sc[8];
  const f32x4 zf = {0.f,0.f,0.f,0.f};
  #pragma unroll
  for (int cg=0;cg<8;cg++){
    bf16x8 kf = *(const bf16x8*)(kt + (wid*32 + cg*16 + lrow)*KT_S + quad*8);
    sc[cg] = __builtin_amdgcn_mfma_f32_16x16x32_bf16(qf, kf, zf, 0,0,0);
  }

  // ---- mask + rpb: hy=cg, hx=lrow -> dy=cg-lyq, dx=lrow-lx ----
  const int lyq = quad>>1;
  #pragma unroll
  for (int cg=0;cg<8;cg++){
    int dy = cg - lyq;
    bool rowok = ((unsigned)dy < 7u) && (lrow < 14);
    #pragma unroll
    for (int r=0;r<4;r++){
      int lx = (quad*4+r)&7;
      int dx = lrow - lx;
      bool in = rowok && ((unsigned)dx < 7u);
      float bias = srpb[in ? (dy*7+dx) : 0];
      sc[cg][r] = in ? (sc[cg][r] + bias) : -1e30f;
    }
  }
  // ---- softmax per pixel-row ----
  float inv[4];
  #pragma unroll
  for (int r=0;r<4;r++){
    float m = sc[0][r];
    #pragma unroll
    for (int cg=1;cg<8;cg++) m = fmaxf(m, sc[cg][r]);
    m = fmaxf(m, __shfl_xor(m,1)); m = fmaxf(m, __shfl_xor(m,2));
    m = fmaxf(m, __shfl_xor(m,4)); m = fmaxf(m, __shfl_xor(m,8));
    float l = 0.f;
    #pragma unroll
    for (int cg=0;cg<8;cg++){ float p = __expf(sc[cg][r]-m); sc[cg][r]=p; l+=p; }
    l += __shfl_xor(l,1); l += __shfl_xor(l,2);
    l += __shfl_xor(l,4); l += __shfl_xor(l,8);
    inv[r]=1.f/l;
  }

  // ---- P write (wave-private; masked cols already 0) ----
  u16* Pw = Pm + wid*16*P_S;
  #pragma unroll
  for (int cg=0;cg<8;cg++){
    #pragma unroll
    for (int r=0;r<4;r++)
      Pw[(quad*4+r)*P_S + cg*16 + lrow] = f2b(sc[cg][r]);
  }
  // no barrier: Pw is read only by this wave; lgkmcnt ordering suffices

  // ---- PV: 8 MFMAs ----
  f32x4 oacc[2] = {zf, zf};
  #pragma unroll
  for (int ks=0;ks<4;ks++){
    bf16x8 pf = *(const bf16x8*)(Pw + lrow*P_S + ks*32 + quad*8);
    #pragma unroll
    for (int cg2=0;cg2<2;cg2++){
      bf16x8 vf = *(const bf16x8*)(vt + (cg2*16+lrow)*VT_S + wid*32 + ks*32 + quad*8);
      oacc[cg2] = __builtin_amdgcn_mfma_f32_16x16x32_bf16(pf, vf, oacc[cg2], 0,0,0);
    }
  }
  #pragma unroll
  for (int r=0;r<4;r++){
    int px = wid*16 + quad*4 + r;
    int tok = b*3136 + (ty + (px>>3))*56 + tx + (px&7);
    #pragma unroll
    for (int cg2=0;cg2<2;cg2++){
      int ch = h*32 + cg2*16 + lrow;
      aout[(size_t)((tok>>5)*16 + (ch>>3))*256 + (tok&31)*8 + (ch&7)]
        = f2b(oacc[cg2][r]*inv[r]);
    }
  }
}

// ---------- K4: PROJ + residual + LN2 + FC1 + GELU + FC2 + residual (unchanged) ----------
__global__ __launch_bounds__(256)
void mega_mlp_kernel(const u16* __restrict__ aout, const float* __restrict__ x,
                     const u16* __restrict__ tproj, const float* __restrict__ bproj,
                     const float* __restrict__ ln2w, const float* __restrict__ ln2b,
                     const u16* __restrict__ tfc1, const float* __restrict__ bfc1,
                     const u16* __restrict__ tfc2, const float* __restrict__ bfc2,
                     float* __restrict__ out)
{
  __shared__ __align__(16) char smem[49664];
  char* lA  = smem;
  char* lB  = smem + 8192;
  char* xn2 = smem + 40960;
  float* redS = (float*)(smem + 49152);
  float* redQ = redS + 64;

  const int tid = threadIdx.x;
  const int lane = tid&63, wid = tid>>6;
  const int quad = lane>>4, lrow = lane&15;
  const int m0 = blockIdx.x*32;
  const int wm = (wid&1)*16, wn = (wid>>1)*64;
  const int half = wid>>1;

  #pragma unroll
  for (int kk=0;kk<2;kk++){
    int i = tid + kk*256;
    async16(aout + (size_t)blockIdx.x*4096 + i*8, lA + i*16);
  }
  #pragma unroll
  for (int kk=0;kk<8;kk++){
    int i = tid + kk*256;
    async16(tproj + (size_t)i*8, lB + i*16);
  }
  __syncthreads();

  f32x4 acc[4] = {};
  #pragma unroll
  for (int ks=0;ks<4;ks++){
    bf16x8 af = ((const bf16x8*)lA)[(ks*4+quad)*32 + wm + lrow];
    #pragma unroll
    for (int j=0;j<4;j++){
      bf16x8 bfr = ((const bf16x8*)lB)[(ks*4+quad)*128 + wn + j*16 + lrow];
      acc[j] = __builtin_amdgcn_mfma_f32_16x16x32_bf16(af, bfr, acc[j], 0,0,0);
    }
  }

  float x1v[4][4];
  float ps[4] = {}, pq[4] = {};
  #pragma unroll
  for (int j=0;j<4;j++){
    int col = wn + j*16 + lrow;
    float bia = bproj[col];
    #pragma unroll
    for (int r=0;r<4;r++){
      int row = m0 + wm + quad*4 + r;
      float val = acc[j][r] + bia + x[(size_t)row*128 + col];
      x1v[j][r] = val;
      ps[r] += val; pq[r] += val*val;
    }
  }
  #pragma unroll
  for (int r=0;r<4;r++){
    #pragma unroll
    for (int off=1; off<16; off<<=1){
      ps[r] += __shfl_xor(ps[r], off);
      pq[r] += __shfl_xor(pq[r], off);
    }
  }
  if (lrow==0){
    #pragma unroll
    for (int r=0;r<4;r++){
      int row = wm + quad*4 + r;
      redS[half*32 + row] = ps[r];
      redQ[half*32 + row] = pq[r];
    }
  }
  __syncthreads();

  {
    float w2[4], b2[4];
    #pragma unroll
    for (int j=0;j<4;j++){ int col = wn+j*16+lrow; w2[j]=ln2w[col]; b2[j]=ln2b[col]; }
    #pragma unroll
    for (int r=0;r<4;r++){
      int row = wm + quad*4 + r;
      float mean = (redS[row] + redS[32+row])*0.0078125f;
      float var  = (redQ[row] + redQ[32+row])*0.0078125f - mean*mean;
      float rstd = rsqrtf(var + 1e-5f);
      #pragma unroll
      for (int j=0;j<4;j++){
        int col = wn + j*16 + lrow;
        u16 hv = f2b((x1v[j][r]-mean)*rstd*w2[j] + b2[j]);
        ((u16*)xn2)[((col>>3)*32 + row)*8 + (col&7)] = hv;
      }
    }
  }
  __syncthreads();

  f32x4 acc3[4] = {};
  for (int nc=0; nc<4; nc++){
    if (nc>0) __syncthreads();
    #pragma unroll
    for (int kk=0;kk<8;kk++){
      int i = tid + kk*256;
      async16(tfc1 + (size_t)nc*16384 + i*8, lB + i*16);
    }
    __syncthreads();

    f32x4 acc2[4] = {};
    #pragma unroll
    for (int ks=0;ks<4;ks++){
      bf16x8 af = ((const bf16x8*)xn2)[(ks*4+quad)*32 + wm + lrow];
      #pragma unroll
      for (int j=0;j<4;j++){
        bf16x8 bfr = ((const bf16x8*)lB)[(ks*4+quad)*128 + wn + j*16 + lrow];
        acc2[j] = __builtin_amdgcn_mfma_f32_16x16x32_bf16(af, bfr, acc2[j], 0,0,0);
      }
    }
    #pragma unroll
    for (int j=0;j<4;j++){
      int col = wn + j*16 + lrow;
      float bia = bfc1[nc*128 + col];
      #pragma unroll
      for (int r=0;r<4;r++){
        int row = wm + quad*4 + r;
        float g = gelu_tanh(acc2[j][r] + bia);
        ((u16*)lA)[((col>>3)*32 + row)*8 + (col&7)] = f2b(g);
      }
    }
    __syncthreads();
    #pragma unroll
    for (int kk=0;kk<8;kk++){
      int i = tid + kk*256;
      async16(tfc2 + (size_t)nc*16384 + i*8, lB + i*16);
    }
    __syncthreads();

    #pragma unroll
    for (int ks=0;ks<4;ks++){
      bf16x8 af = ((const bf16x8*)lA)[(ks*4+quad)*32 + wm + lrow];
      #pragma unroll
      for (int j=0;j<4;j++){
        bf16x8 bfr = ((const bf16x8*)lB)[(ks*4+quad)*128 + wn + j*16 + lrow];
        acc3[j] = __builtin_amdgcn_mfma_f32_16x16x32_bf16(af, bfr, acc3[j], 0,0,0);
      }
    }
  }

  #pragma unroll
  for (int j=0;j<4;j++){
    int col = wn + j*16 + lrow;
    float bia = bfc2[col];
    #pragma unroll
    for (int r=0;r<4;r++){
      int row = m0 + wm + quad*4 + r;
      out[(size_t)row*128 + col] = acc3[j][r] + bia + x1v[j][r];
    }
  }
}

extern "C" void kernel_launch(void* const* d_in, const int* in_sizes, int n_in,
                              void* d_out, int out_size, void* d_ws, size_t ws_size,
                              hipStream_t stream)
{
  const float* x     =(const float*)d_in[0];
  const float* ln1w  =(const float*)d_in[1];
  const float* ln1b  =(const float*)d_in[2];
  const float* wqkv  =(const float*)d_in[3];
  const float* bqkv  =(const float*)d_in[4];
  const float* rpb   =(const float*)d_in[5];
  const float* wproj =(const float*)d_in[6];
  const float* bproj =(const float*)d_in[7];
  const float* ln2w  =(const float*)d_in[8];
  const float* ln2b  =(const float*)d_in[9];
  const float* wfc1  =(const float*)d_in[10];
  const float* bfc1  =(const float*)d_in[11];
  const float* wfc2  =(const float*)d_in[12];
  const float* bfc2  =(const float*)d_in[13];

  char* ws=(char*)d_ws;
  size_t o=0;
  u16* tqkv =(u16*)(ws+o); o+=98304;
  u16* tproj=(u16*)(ws+o); o+=32768;
  u16* tfc1 =(u16*)(ws+o); o+=131072;
  u16* tfc2 =(u16*)(ws+o); o+=131072;
  u16* aout =(u16*)(ws+o); o+=3211264;
  u16* qb   =(u16*)(ws+o); o+=3211264;
  u16* kb   =(u16*)(ws+o); o+=3211264;
  u16* vb3  =(u16*)(ws+o); o+=4194304;   // planar padded V [16][32][64*64]

  prep_kernel<<<1792,256,0,stream>>>(wqkv,wproj,wfc1,wfc2,tqkv,tproj,tfc1,tfc2,vb3);
  qkv_ln_kernel<<<dim3(392,3),256,0,stream>>>(x,ln1w,ln1b,tqkv,bqkv,qb,kb,vb3);
  attn_kernel<<<dim3(49,16),256,0,stream>>>(qb,kb,vb3,rpb,aout);
  mega_mlp_kernel<<<392,256,0,stream>>>(aout,x,tproj,bproj,ln2w,ln2b,
                                        tfc1,bfc1,tfc2,bfc2,(float*)d_out);
}